// Round 9
// baseline (332.483 us; speedup 1.0000x reference)
//
#include <hip/hip_runtime.h>
#include <cmath>

#define B_ 8
#define C_ 64
#define M_ 256
#define N_ 256
#define PLANE_ (M_*N_)          // 65536
#define PIX_ (B_*PLANE_)        // 524288
#define THRESH_ 0.8f
#define EPS_ 1e-5f

typedef float nt_f4 __attribute__((ext_vector_type(4)));   // for nontemporal stores

// ---------------- K1: partial channel avg & max, 4-way channel split ----------------
// grid (512, 4): quarter h reduces channels [16h,16h+16). 8 partial planes:
// part[(2h+0)*PIX_ + g] = sum, part[(2h+1)*PIX_ + g] = max. K2 combines.
// Occupancy: 2048 blocks = 8 blocks/CU = 32 waves/CU (vs 2 blocks/CU before).
// Also zeroes the 257 accumulator words (S,Q,S1,Q1,cnt).
__global__ void k_avgmax(const float* __restrict__ x,
                         float* __restrict__ part, float* __restrict__ acc) {
    int h = blockIdx.y;
    if (blockIdx.x == 0 && h == 0) {
        if (threadIdx.x < 4 * C_) acc[threadIdx.x] = 0.f;   // S,Q,S1,Q1 (256 words)
        if (threadIdx.x == 0) acc[4 * C_] = 0.f;            // cnt (bit pattern 0)
    }
    int idx4 = (blockIdx.x * blockDim.x + threadIdx.x) * 4;   // global pixel (B*M*N)
    int b = idx4 >> 16;                // / PLANE_
    int p = idx4 & (PLANE_ - 1);
    const float* xb = x + (size_t)b * C_ * PLANE_ + (size_t)(h * 16) * PLANE_ + p;
    float4 s = make_float4(0.f, 0.f, 0.f, 0.f);
    float4 mx = make_float4(-INFINITY, -INFINITY, -INFINITY, -INFINITY);
    #pragma unroll
    for (int c = 0; c < 16; ++c) {
        float4 v = *(const float4*)(xb + (size_t)c * PLANE_);
        s.x += v.x; s.y += v.y; s.z += v.z; s.w += v.w;
        mx.x = fmaxf(mx.x, v.x); mx.y = fmaxf(mx.y, v.y);
        mx.z = fmaxf(mx.z, v.z); mx.w = fmaxf(mx.w, v.w);
    }
    *(float4*)(part + (size_t)(2 * h + 0) * PIX_ + idx4) = s;
    *(float4*)(part + (size_t)(2 * h + 1) * PIX_ + idx4) = mx;
}

// ------- K2f: fused LDS-tiled sa conv + sigmoid + gamma/beta convs + mask + count -------
// Staging combines the 4 channel-quarter partials: avg=(s0+s1+s2+s3)/64, max=max4.
#define TW_ 64
#define TH_ 16
#define SAW_ (TW_+6)   // 70
#define SAH_ (TH_+6)   // 22
#define LDW_ (TW_+12)  // 76
#define LDH_ (TH_+12)  // 28

__global__ void k_sa_fused(const float* __restrict__ part,
                           const float* __restrict__ w1,
                           const float* __restrict__ wg, const float* __restrict__ bgp,
                           const float* __restrict__ wb, const float* __restrict__ bbp,
                           float* __restrict__ gammap, float* __restrict__ betap,
                           unsigned char* __restrict__ maskp, int* __restrict__ cntp) {
    __shared__ float sA[LDH_][LDW_];
    __shared__ float sM[LDH_][LDW_];
    __shared__ float sSA[SAH_][SAW_];
    __shared__ float w[196];           // [0:98) = w1 (avg,max), [98:147) = wg, [147:196) = wb
    __shared__ int bcnt;
    int tid = threadIdx.x;
    if (tid < 98) w[tid] = w1[tid];
    else if (tid < 196) w[tid] = (tid < 147) ? wg[tid - 98] : wb[tid - 147];
    if (tid == 196) bcnt = 0;

    int tileid = blockIdx.x;                 // 64 tiles per plane (16 rows x 4 cols)
    int b = blockIdx.y;
    int ti0 = (tileid >> 2) * TH_;
    int tj0 = (tileid & 3) * TW_;
    size_t bo = (size_t)b * PLANE_;
    const float* s0 = part + 0 * (size_t)PIX_ + bo;
    const float* m0 = part + 1 * (size_t)PIX_ + bo;
    const float* s1p = part + 2 * (size_t)PIX_ + bo;
    const float* m1p = part + 3 * (size_t)PIX_ + bo;
    const float* s2p = part + 4 * (size_t)PIX_ + bo;
    const float* m2p = part + 5 * (size_t)PIX_ + bo;
    const float* s3p = part + 6 * (size_t)PIX_ + bo;
    const float* m3p = part + 7 * (size_t)PIX_ + bo;

    // stage combined avg/max tile + halo 6 (zero-fill outside the plane)
    for (int idx = tid; idx < LDH_ * LDW_; idx += 256) {
        int li = idx / LDW_;
        int lj = idx - li * LDW_;
        int gi = ti0 - 6 + li, gj = tj0 - 6 + lj;
        bool ok = ((unsigned)gi < (unsigned)M_) && ((unsigned)gj < (unsigned)N_);
        float av = 0.f, mv = 0.f;
        if (ok) {
            int o = gi * N_ + gj;
            av = (s0[o] + s1p[o] + s2p[o] + s3p[o]) * (1.f / C_);
            mv = fmaxf(fmaxf(m0[o], m1p[o]), fmaxf(m2p[o], m3p[o]));
        }
        sA[li][lj] = av;
        sM[li][lj] = mv;
    }
    __syncthreads();

    // sa_map on tile + halo 3. Outside-plane sa entries must be ZERO (conv zero-pads
    // sa_map itself), not sigmoid(0).
    for (int idx = tid; idx < SAH_ * SAW_; idx += 256) {
        int si = idx / SAW_;
        int sj = idx - si * SAW_;
        int gi = ti0 - 3 + si, gj = tj0 - 3 + sj;
        float v = 0.f;
        if ((unsigned)gi < (unsigned)M_ && (unsigned)gj < (unsigned)N_) {
            float acc = 0.f;
            #pragma unroll
            for (int dh = 0; dh < 7; ++dh) {
                #pragma unroll
                for (int dw = 0; dw < 7; ++dw) {
                    acc += sA[si + dh][sj + dw] * w[dh * 7 + dw]
                         + sM[si + dh][sj + dw] * w[49 + dh * 7 + dw];
                }
            }
            v = 1.f / (1.f + expf(-acc));
        }
        sSA[si][sj] = v;
    }
    __syncthreads();

    // gamma/beta convs on the tile, mask byte, block count
    float bgv = bgp[0], bbv = bbp[0];
    int lcnt = 0;
    #pragma unroll
    for (int k = 0; k < 4; ++k) {
        int p = k * 256 + tid;
        int ti = p >> 6, tj = p & 63;
        float g = 0.f, be = 0.f;
        #pragma unroll
        for (int dh = 0; dh < 7; ++dh) {
            #pragma unroll
            for (int dw = 0; dw < 7; ++dw) {
                float v = sSA[ti + dh][tj + dw];
                g  += v * w[98 + dh * 7 + dw];
                be += v * w[147 + dh * 7 + dw];
            }
        }
        int idx = b * PLANE_ + (ti0 + ti) * N_ + (tj0 + tj);
        gammap[idx] = g + bgv;
        betap[idx]  = be + bbv;
        int mk = (sSA[ti + 3][tj + 3] >= THRESH_) ? 1 : 0;
        maskp[idx] = (unsigned char)mk;
        lcnt += mk;
    }
    for (int off = 32; off > 0; off >>= 1) lcnt += __shfl_down(lcnt, off, 64);
    if ((tid & 63) == 0) atomicAdd(&bcnt, lcnt);
    __syncthreads();
    if (tid == 0) atomicAdd(cntp, bcnt);
}

// -------- K3: per-channel sums: S, Q, S1(masked), Q1(masked) ----------
__global__ void k_sums(const float* __restrict__ x, const unsigned char* __restrict__ maskp,
                       float* __restrict__ S, float* __restrict__ Q,
                       float* __restrict__ S1, float* __restrict__ Q1) {
    int chunk = blockIdx.x;          // 8 chunks of 8192 per plane
    int c = blockIdx.y;
    int b = blockIdx.z;
    const float* xp = x + ((size_t)(b * C_ + c)) * PLANE_ + chunk * 8192;
    const unsigned char* mp = maskp + (size_t)b * PLANE_ + chunk * 8192;
    float s = 0.f, q = 0.f, s1 = 0.f, q1 = 0.f;
    #pragma unroll
    for (int k = 0; k < 8; ++k) {
        int t = (k * 256 + threadIdx.x) * 4;
        float4 v = *(const float4*)(xp + t);
        uchar4 mm = *(const uchar4*)(mp + t);
        float m0 = (float)mm.x, m1 = (float)mm.y, m2 = (float)mm.z, m3 = (float)mm.w;
        s  += v.x + v.y + v.z + v.w;
        q  += v.x * v.x + v.y * v.y + v.z * v.z + v.w * v.w;
        s1 += v.x * m0 + v.y * m1 + v.z * m2 + v.w * m3;
        q1 += v.x * v.x * m0 + v.y * v.y * m1 + v.z * v.z * m2 + v.w * v.w * m3;
    }
    for (int off = 32; off > 0; off >>= 1) {
        s  += __shfl_down(s, off, 64);
        q  += __shfl_down(q, off, 64);
        s1 += __shfl_down(s1, off, 64);
        q1 += __shfl_down(q1, off, 64);
    }
    __shared__ float ls[4][4];
    int wave = threadIdx.x >> 6, lane = threadIdx.x & 63;
    if (lane == 0) { ls[wave][0] = s; ls[wave][1] = q; ls[wave][2] = s1; ls[wave][3] = q1; }
    __syncthreads();
    if (threadIdx.x == 0) {
        float ts = 0.f, tq = 0.f, ts1 = 0.f, tq1 = 0.f;
        #pragma unroll
        for (int wv = 0; wv < 4; ++wv) { ts += ls[wv][0]; tq += ls[wv][1]; ts1 += ls[wv][2]; tq1 += ls[wv][3]; }
        atomicAdd(&S[c], ts); atomicAdd(&Q[c], tq);
        atomicAdd(&S1[c], ts1); atomicAdd(&Q1[c], tq1);
    }
}

// -------- K5: coefficients inline + final elementwise, 8 channels per block ----------
__global__ void k_final(const float* __restrict__ x, const unsigned char* __restrict__ maskp,
                        const float* __restrict__ gammap, const float* __restrict__ betap,
                        const float* __restrict__ S, const float* __restrict__ Q,
                        const float* __restrict__ S1, const float* __restrict__ Q1,
                        const int* __restrict__ cntp,
                        float* __restrict__ out) {
    int c0 = blockIdx.y * 8;
    int b = blockIdx.z;
    const float P = (float)PIX_;
    int cnt1 = *cntp;
    float fc1 = (float)cnt1;
    float fc0 = P - fc1;
    float Sr1 = (cnt1 == 0) ? 1.f : fc1;
    float Sr0 = (cnt1 == PIX_) ? 1.f : fc0;
    float sq1 = sqrtf(Sr1 / P), sq0 = sqrtf(Sr0 / P);
    float ma[8], mb[8], ua[8], ub[8];
    #pragma unroll
    for (int cc = 0; cc < 8; ++cc) {
        int c = c0 + cc;
        float Sv = S[c], Qv = Q[c], S1v = S1[c], Q1v = Q1[c];
        float S0v = Sv - S1v, Q0v = Qv - Q1v;
        float mu1 = S1v / Sr1;
        float mu0 = S0v / Sr0;
        float m1 = (S1v + fc0 * mu1) / P;
        float v1 = fmaxf((Q1v + fc0 * mu1 * mu1) / P - m1 * m1, 0.f);
        float m0 = (S0v + fc1 * mu0) / P;
        float v0 = fmaxf((Q0v + fc1 * mu0 * mu0) / P - m0 * m0, 0.f);
        float A1 = rsqrtf(v1 + EPS_) * sq1;
        float A0 = rsqrtf(v0 + EPS_) * sq0;
        float B1 = (mu1 - m1) * A1;
        float B0 = (mu0 - m0) * A0;
        ma[cc] = A1; mb[cc] = -m1 * A1 + B0;   // masked:   x*A1 - m1*A1 + B0
        ua[cc] = A0; ub[cc] = -m0 * A0 + B1;   // unmasked: x*A0 - m0*A0 + B1
    }

    int p0 = blockIdx.x * 1024 + threadIdx.x * 4;     // pixel within plane
    int pp = b * PLANE_ + p0;
    float4 gv = *(const float4*)(gammap + pp);
    float4 bv = *(const float4*)(betap + pp);
    uchar4 mv = *(const uchar4*)(maskp + pp);
    float4 G = make_float4(1.f + gv.x, 1.f + gv.y, 1.f + gv.z, 1.f + gv.w);
    #pragma unroll
    for (int cc = 0; cc < 8; ++cc) {
        size_t base = ((size_t)(b * C_ + c0 + cc)) * PLANE_ + p0;
        float4 xv = *(const float4*)(x + base);
        nt_f4 o;
        o.x = (mv.x ? xv.x * ma[cc] + mb[cc] : xv.x * ua[cc] + ub[cc]) * G.x + bv.x;
        o.y = (mv.y ? xv.y * ma[cc] + mb[cc] : xv.y * ua[cc] + ub[cc]) * G.y + bv.y;
        o.z = (mv.z ? xv.z * ma[cc] + mb[cc] : xv.z * ua[cc] + ub[cc]) * G.z + bv.z;
        o.w = (mv.w ? xv.w * ma[cc] + mb[cc] : xv.w * ua[cc] + ub[cc]) * G.w + bv.w;
        __builtin_nontemporal_store(o, (nt_f4*)(out + base));
    }
}

extern "C" void kernel_launch(void* const* d_in, const int* in_sizes, int n_in,
                              void* d_out, int out_size, void* d_ws, size_t ws_size,
                              hipStream_t stream) {
    const float* x  = (const float*)d_in[0];
    const float* w1 = (const float*)d_in[1];
    const float* wg = (const float*)d_in[2];
    const float* bg = (const float*)d_in[3];
    const float* wb = (const float*)d_in[4];
    const float* bb = (const float*)d_in[5];
    float* out = (float*)d_out;

    float* ws = (float*)d_ws;
    float* part   = ws;                       // 8 * PIX_ (partial sum/max planes, 16 MB)
    float* gammap = part + 8 * (size_t)PIX_;  // 524288
    float* betap  = gammap + PIX_;            // 524288
    float* S   = betap + PIX_;                // 64
    float* Q   = S + C_;                      // 64
    float* S1  = Q + C_;                      // 64
    float* Q1  = S1 + C_;                     // 64
    int*   cnt = (int*)(Q1 + C_);             // 1
    unsigned char* maskp = (unsigned char*)(cnt + 1);  // 524288 bytes

    // K1: partial channel avg/max, 4-way channel split (+ zero accumulators)
    dim3 g1(PIX_ / (256 * 4), 4);
    k_avgmax<<<g1, 256, 0, stream>>>(x, part, S);
    // K2f: combine partials + sa conv + sigmoid + gamma/beta convs + mask + count
    dim3 g2(64, B_);
    k_sa_fused<<<g2, 256, 0, stream>>>(part, w1, wg, bg, wb, bb,
                                       gammap, betap, maskp, cnt);
    // K3: per-channel sums
    dim3 g3(8, C_, B_);
    k_sums<<<g3, 256, 0, stream>>>(x, maskp, S, Q, S1, Q1);
    // K5: coefficients inline + final (8 channels per block)
    dim3 g5(PLANE_ / 1024, C_ / 8, B_);
    k_final<<<g5, 256, 0, stream>>>(x, maskp, gammap, betap, S, Q, S1, Q1, cnt, out);
}